// Round 20
// baseline (221.650 us; speedup 1.0000x reference)
//
#include <hip/hip_runtime.h>

typedef _Float16 h8 __attribute__((ext_vector_type(8)));
typedef _Float16 h4 __attribute__((ext_vector_type(4)));
typedef _Float16 h2 __attribute__((ext_vector_type(2)));

// Problem constants (reference: B,M,N,L,S,KERN = 4,256,256,24,22,256; KERN==M → tile is identity)
constexpr int B_ = 4, M_ = 256, N_ = 256, L_ = 24, S_ = 22;
constexpr int ASP_ = 13;    // A8t [n][sp] pitch in h8 cells (208B/row)
constexpr int XTP_ = 25;    // XT2 [n][l] row pitch in h2 (4B) cells (25-dword stride, conflict-free)
constexpr int NYR_ = 280;   // Y rows per plane (279 used: 256 main + 23 tail)

// LDS layout (bytes). 1 wg/CU is an empirical law on this harness (R21/R22/
// R24: occupancy == one wg's waves across VGPR 64..232, LDS 65..154KB).
constexpr int A_BYTES  = N_ * ASP_ * 16;           // 53,248  A8t[n][sp]: sp=s/2, h8 = {s_even h4, s_odd h4}
constexpr int XT_BYTES = N_ * XTP_ * 4;            // 25,600  x[n][l] h2 over this block's b-pair
constexpr int Y_BYTES  = 6 * NYR_ * 16;            // 26,880  SIX Y planes (16B cells: 2 h4)
constexpr int XT_OFF   = A_BYTES;                  // 53,248
constexpr int Y_OFF    = XT_OFF + XT_BYTES;        // 78,848 (16B-aligned)
constexpr int WMAX_OFF = Y_OFF + Y_BYTES;          // 105,728
constexpr int LDS_BYTES = WMAX_OFF + 32;           // 105,760 <= 163,840
constexpr int XT_OFF_H2 = XT_OFF / 4;              // 13,312
constexpr int Y_OFF_H4  = Y_OFF / 8;               //  9,856
constexpr int Y_OFF_H8  = Y_OFF / 16;              //  4,928

// Color bases as COMPILE-TIME constants (validated R6/R8/R9/R10):
constexpr float FR[L_] = {  // mu = 620
    6.252150e-05f, 1.904358e-04f, 5.418690e-04f, 1.440515e-03f, 3.577400e-03f,
    8.299750e-03f, 1.798893e-02f, 3.642490e-02f, 6.890060e-02f, 1.217600e-01f,
    2.010120e-01f, 3.100190e-01f, 4.466857e-01f, 6.012587e-01f, 7.560710e-01f,
    8.881955e-01f, 9.747661e-01f, 9.993953e-01f, 9.572367e-01f, 8.565352e-01f,
    7.160078e-01f, 5.591580e-01f, 4.079402e-01f, 2.780373e-01f};
constexpr float FG[L_] = {  // mu = 550
    1.110900e-02f, 2.348440e-02f, 4.638000e-02f, 8.557090e-02f, 1.474900e-01f,
    2.374920e-01f, 3.572560e-01f, 5.020580e-01f, 6.591400e-01f, 8.084270e-01f,
    9.262975e-01f, 9.915296e-01f, 9.915296e-01f, 9.262975e-01f, 8.084270e-01f,
    6.591400e-01f, 5.020580e-01f, 3.572560e-01f, 2.374920e-01f, 1.474900e-01f,
    8.557090e-02f, 4.638000e-02f, 2.348440e-02f, 1.110900e-02f};
constexpr float FB[L_] = {  // mu = 450 (pairs with wb)
    6.065307e-01f, 7.609727e-01f, 8.919300e-01f, 9.766475e-01f, 9.990553e-01f,
    9.547420e-01f, 8.523698e-01f, 7.109096e-01f, 5.539184e-01f, 4.032022e-01f,
    2.741855e-01f, 1.741852e-01f, 1.033776e-01f, 5.731640e-02f, 2.968800e-02f,
    1.436580e-02f, 6.494090e-03f, 2.742560e-03f, 1.079230e-03f, 3.988070e-04f,
    1.369660e-04f, 4.417250e-05f, 1.327420e-05f, 3.726650e-06f};
constexpr float FC[L_] = {  // mu = 500 (pairs with wc)
    1.353353e-01f, 2.204053e-01f, 3.353338e-01f, 4.766271e-01f, 6.328849e-01f,
    7.850828e-01f, 9.098110e-01f, 9.849909e-01f, 9.962264e-01f, 9.413024e-01f,
    8.308921e-01f, 6.851808e-01f, 5.278508e-01f, 3.798934e-01f, 2.554222e-01f,
    1.604349e-01f, 9.414200e-02f, 5.160780e-02f, 2.642960e-02f, 1.264440e-02f,
    5.651680e-03f, 2.359870e-03f, 9.205430e-04f, 3.354630e-04f};

__device__ __forceinline__ float fdot2(h2 a, h2 b, float c) {
    return __builtin_amdgcn_fdot2(a, b, c, false);
}

// R27 (third submission — two infra failures, never executed) = R26
// (77.6us: mega-phases, 3 barriers, no spill) + two ILP levers:
//  1) A transposed in LDS to [n][shot-pair] h8 cells (pitch 13 = 208B):
//     a 4-shot quad = 2 ds_read_b128 (was 4 b64). Phase-A loads 5->3 per
//     iter; phase-B q reads 4->2.
//  2) Mega-A loop interchange: l OUTER, sq INNER (unrolled). Per l: idx and
//     xv computed once for all 6 sq; 13 independent loads feed 48 indep
//     acc chains (lean); no LDS writes in-loop -> deep pipelining. Wave 0
//     runs two 3-sq passes (dual main+tail acc stays at 48 floats).
//     sched_barrier(0) every 2 l-iters caps load hoisting (R17 containment).
// Falsifiers: WRITE >40MB = spill (shrink sq-inner); dur ~77 w/ VALU ~28%
// = loads still not pipelined; bank-conflict >>115K = A8 pitch aliasing.
__global__ __launch_bounds__(256)
void cassi_fused(
    const float* __restrict__ x,
    const float* __restrict__ wr, const float* __restrict__ wg,
    const float* __restrict__ wb, const float* __restrict__ wc,
    float* __restrict__ out, float* __restrict__ bmax_out)
{
    __shared__ __align__(16) char lds_raw[LDS_BYTES];
    h8* A8  = reinterpret_cast<h8*>(lds_raw);                 // [n][sp] cells
    h4* A4t = reinterpret_cast<h4*>(lds_raw);                 // h4 view for staging
    h2* XT2 = reinterpret_cast<h2*>(lds_raw) + XT_OFF_H2;
    h4* Y4  = reinterpret_cast<h4*>(lds_raw) + Y_OFF_H4;
    h8* Y8  = reinterpret_cast<h8*>(lds_raw) + Y_OFF_H8;
    float* wmax = reinterpret_cast<float*>(lds_raw + WMAX_OFF);

    const int t  = threadIdx.x;          // 0..255: column
    const int m  = blockIdx.x >> 1;      // row
    const int bp = blockIdx.x & 1;       // b-pair: handles b = 2bp, 2bp+1
    const int b0 = 2 * bp, b1 = 2 * bp + 1;

    // ---- Staging ----
    // zero pad cell sp=11 (s=22,23) for every n: one h8 store per thread.
    {
        h8 z = {};
        A8[t * ASP_ + 11] = z;
    }
    // x: thread t stages column n=t for THIS block's two b -> XT2[n][l] h2.
    {
        const float4* xa = reinterpret_cast<const float4*>(x + ((b0 * M_ + m) * N_ + t) * L_);
        const float4* xb = reinterpret_cast<const float4*>(x + ((b1 * M_ + m) * N_ + t) * L_);
        #pragma unroll
        for (int i = 0; i < 6; ++i) {
            const float4 va = xa[i], vb = xb[i];
            h2 c0; c0.x=(_Float16)va.x; c0.y=(_Float16)vb.x;
            h2 c1; c1.x=(_Float16)va.y; c1.y=(_Float16)vb.y;
            h2 c2; c2.x=(_Float16)va.z; c2.y=(_Float16)vb.z;
            h2 c3; c3.x=(_Float16)va.w; c3.y=(_Float16)vb.w;
            XT2[t * XTP_ + 4 * i + 0] = c0;
            XT2[t * XTP_ + 4 * i + 1] = c1;
            XT2[t * XTP_ + 4 * i + 2] = c2;
            XT2[t * XTP_ + 4 * i + 3] = c3;
        }
    }
    // weights: coalesced, normalized once, h4 into TRANSPOSED A8t[n][sp]
    // (h4 half-cell: byte (n*13 + s/2)*16 + (s&1)*8). unroll 2 pipeline.
    {
        const float* wrm = wr + m * (N_ * S_);
        const float* wgm = wg + m * (N_ * S_);
        const float* wbm = wb + m * (N_ * S_);
        const float* wcm = wc + m * (N_ * S_);
        #pragma unroll 2
        for (int i = 0; i < S_; ++i) {
            const int f = i * 256 + t;
            const float r = wrm[f], g = wgm[f], u = wbm[f], v = wcm[f];
            const int n = f / S_, s = f - n * S_;
            const float inv = 1.f / (r + g + u + v);
            h4 p;
            p.x = (_Float16)(r * inv); p.y = (_Float16)(g * inv);
            p.z = (_Float16)(u * inv); p.w = (_Float16)(v * inv);
            A4t[(n * ASP_ + (s >> 1)) * 2 + (s & 1)] = p;
        }
    }
    __syncthreads();

    // ---- Phase A (mega, l-outer): all planes accumulated in registers,
    // Y written at the end. No LDS writes inside the l loop -> deep load
    // pipelining. Wave-uniform branch: wave 0 (t<64) dual main+tail in two
    // 3-sq passes; waves 1-3 all 6 sq at once (idx = t-l >= 41 always).
    if (t >= 64) {
        float4 aM0[6], aM1[6];
        #pragma unroll
        for (int sq = 0; sq < 6; ++sq) {
            aM0[sq].x=aM0[sq].y=aM0[sq].z=aM0[sq].w=0.f;
            aM1[sq] = aM0[sq];
        }
        #pragma unroll
        for (int l = 0; l < L_; ++l) {
            h2 f01; f01.x = (_Float16)FR[l]; f01.y = (_Float16)FG[l];
            h2 f23; f23.x = (_Float16)FB[l]; f23.y = (_Float16)FC[l];
            const int idx = t - l;                       // >= 41
            const h2 xq = XT2[idx * XTP_ + l];
            const float xv0 = (float)xq.x, xv1 = (float)xq.y;
            const int abase = idx * ASP_;
            #pragma unroll
            for (int sq = 0; sq < 6; ++sq) {
                const h8 c01 = A8[abase + 2 * sq];
                const h8 c23 = A8[abase + 2 * sq + 1];
                const float g0 = fdot2(h2{c01[0],c01[1]}, f01, fdot2(h2{c01[2],c01[3]}, f23, 0.f));
                const float g1 = fdot2(h2{c01[4],c01[5]}, f01, fdot2(h2{c01[6],c01[7]}, f23, 0.f));
                const float g2 = fdot2(h2{c23[0],c23[1]}, f01, fdot2(h2{c23[2],c23[3]}, f23, 0.f));
                const float g3 = fdot2(h2{c23[4],c23[5]}, f01, fdot2(h2{c23[6],c23[7]}, f23, 0.f));
                aM0[sq].x += g0 * xv0; aM1[sq].x += g0 * xv1;
                aM0[sq].y += g1 * xv0; aM1[sq].y += g1 * xv1;
                aM0[sq].z += g2 * xv0; aM1[sq].z += g2 * xv1;
                aM0[sq].w += g3 * xv0; aM1[sq].w += g3 * xv1;
            }
            if ((l & 1) == 1) __builtin_amdgcn_sched_barrier(0);
        }
        #pragma unroll
        for (int sq = 0; sq < 6; ++sq) {
            h4 pm0, pm1;
            pm0.x=(_Float16)aM0[sq].x; pm0.y=(_Float16)aM0[sq].y;
            pm0.z=(_Float16)aM0[sq].z; pm0.w=(_Float16)aM0[sq].w;
            pm1.x=(_Float16)aM1[sq].x; pm1.y=(_Float16)aM1[sq].y;
            pm1.z=(_Float16)aM1[sq].z; pm1.w=(_Float16)aM1[sq].w;
            Y4[(sq * NYR_ + t) * 2 + 0] = pm0;
            Y4[(sq * NYR_ + t) * 2 + 1] = pm1;
        }
    } else {
        #pragma unroll 1
        for (int p = 0; p < 2; ++p) {
            float4 aM0[3], aM1[3], aT0[3], aT1[3];
            #pragma unroll
            for (int j = 0; j < 3; ++j) {
                aM0[j].x=aM0[j].y=aM0[j].z=aM0[j].w=0.f;
                aM1[j]=aM0[j]; aT0[j]=aM0[j]; aT1[j]=aM0[j];
            }
            #pragma unroll
            for (int l = 0; l < L_; ++l) {
                h2 f01; f01.x = (_Float16)FR[l]; f01.y = (_Float16)FG[l];
                h2 f23; f23.x = (_Float16)FB[l]; f23.y = (_Float16)FC[l];
                const bool mn = (l <= t);
                const int idx = mn ? (t - l) : (256 + t - l);
                const float mm = mn ? 1.f : 0.f;
                const h2 xq = XT2[idx * XTP_ + l];
                const float xv0 = (float)xq.x, xv1 = (float)xq.y;
                const int abase = idx * ASP_;
                #pragma unroll
                for (int j = 0; j < 3; ++j) {
                    const int sq = 3 * p + j;
                    const h8 c01 = A8[abase + 2 * sq];
                    const h8 c23 = A8[abase + 2 * sq + 1];
                    const float g0 = fdot2(h2{c01[0],c01[1]}, f01, fdot2(h2{c01[2],c01[3]}, f23, 0.f));
                    const float g1 = fdot2(h2{c01[4],c01[5]}, f01, fdot2(h2{c01[6],c01[7]}, f23, 0.f));
                    const float g2 = fdot2(h2{c23[0],c23[1]}, f01, fdot2(h2{c23[2],c23[3]}, f23, 0.f));
                    const float g3 = fdot2(h2{c23[4],c23[5]}, f01, fdot2(h2{c23[6],c23[7]}, f23, 0.f));
                    const float gm0 = g0 * mm, gt0 = g0 - gm0;
                    const float gm1 = g1 * mm, gt1 = g1 - gm1;
                    const float gm2 = g2 * mm, gt2 = g2 - gm2;
                    const float gm3 = g3 * mm, gt3 = g3 - gm3;
                    aM0[j].x += gm0 * xv0; aT0[j].x += gt0 * xv0;
                    aM0[j].y += gm1 * xv0; aT0[j].y += gt1 * xv0;
                    aM0[j].z += gm2 * xv0; aT0[j].z += gt2 * xv0;
                    aM0[j].w += gm3 * xv0; aT0[j].w += gt3 * xv0;
                    aM1[j].x += gm0 * xv1; aT1[j].x += gt0 * xv1;
                    aM1[j].y += gm1 * xv1; aT1[j].y += gt1 * xv1;
                    aM1[j].z += gm2 * xv1; aT1[j].z += gt2 * xv1;
                    aM1[j].w += gm3 * xv1; aT1[j].w += gt3 * xv1;
                }
                if ((l % 3) == 2) __builtin_amdgcn_sched_barrier(0);
            }
            #pragma unroll
            for (int j = 0; j < 3; ++j) {
                const int sq = 3 * p + j;
                h4 pm0, pm1;
                pm0.x=(_Float16)aM0[j].x; pm0.y=(_Float16)aM0[j].y;
                pm0.z=(_Float16)aM0[j].z; pm0.w=(_Float16)aM0[j].w;
                pm1.x=(_Float16)aM1[j].x; pm1.y=(_Float16)aM1[j].y;
                pm1.z=(_Float16)aM1[j].z; pm1.w=(_Float16)aM1[j].w;
                Y4[(sq * NYR_ + t) * 2 + 0] = pm0;
                Y4[(sq * NYR_ + t) * 2 + 1] = pm1;
                if (t < 23) {
                    h4 pt0, pt1;
                    pt0.x=(_Float16)aT0[j].x; pt0.y=(_Float16)aT0[j].y;
                    pt0.z=(_Float16)aT0[j].z; pt0.w=(_Float16)aT0[j].w;
                    pt1.x=(_Float16)aT1[j].x; pt1.y=(_Float16)aT1[j].y;
                    pt1.z=(_Float16)aT1[j].z; pt1.w=(_Float16)aT1[j].w;
                    Y4[(sq * NYR_ + 256 + t) * 2 + 0] = pt0;
                    Y4[(sq * NYR_ + 256 + t) * 2 + 1] = pt1;
                }
            }
        }
    }
    __syncthreads();

    // ---- Phase B (mega): 6 B-passes, Y read-only, NO barriers.
    float X0[L_], X1[L_];
    #pragma unroll
    for (int l = 0; l < L_; ++l) { X0[l] = 0.f; X1[l] = 0.f; }
    float vmax = 0.f;

    #pragma unroll 1
    for (int sq = 0; sq < 6; ++sq) {
        const h8 qc01 = A8[t * ASP_ + 2 * sq];
        const h8 qc23 = A8[t * ASP_ + 2 * sq + 1];
        const int ybase = sq * NYR_ + t;
        #pragma unroll
        for (int l = 0; l < L_; ++l) {
            h2 f01; f01.x = (_Float16)FR[l]; f01.y = (_Float16)FG[l];
            h2 f23; f23.x = (_Float16)FB[l]; f23.y = (_Float16)FC[l];
            const float g0 = fdot2(h2{qc01[0],qc01[1]}, f01, fdot2(h2{qc01[2],qc01[3]}, f23, 0.f));
            const float g1 = fdot2(h2{qc01[4],qc01[5]}, f01, fdot2(h2{qc01[6],qc01[7]}, f23, 0.f));
            const float g2 = fdot2(h2{qc23[0],qc23[1]}, f01, fdot2(h2{qc23[2],qc23[3]}, f23, 0.f));
            const float g3 = fdot2(h2{qc23[4],qc23[5]}, f01, fdot2(h2{qc23[6],qc23[7]}, f23, 0.f));
            h2 G01; G01.x = (_Float16)g0; G01.y = (_Float16)g1;
            h2 G23; G23.x = (_Float16)g2; G23.y = (_Float16)g3;
            const h8 y = Y8[ybase + l];
            X0[l] = fdot2(G01, h2{y[0],y[1]}, fdot2(G23, h2{y[2],y[3]}, X0[l]));
            X1[l] = fdot2(G01, h2{y[4],y[5]}, fdot2(G23, h2{y[6],y[7]}, X1[l]));
        }
    }

    // ---- Output: contiguous 96B burst per (b, row t) + running max.
    {
        float4* o0 = reinterpret_cast<float4*>(out + ((b0 * M_ + m) * N_ + t) * L_);
        float4* o1 = reinterpret_cast<float4*>(out + ((b1 * M_ + m) * N_ + t) * L_);
        #pragma unroll
        for (int i = 0; i < 6; ++i) {
            float4 v0, v1;
            v0.x = X0[4*i+0]; v0.y = X0[4*i+1]; v0.z = X0[4*i+2]; v0.w = X0[4*i+3];
            v1.x = X1[4*i+0]; v1.y = X1[4*i+1]; v1.z = X1[4*i+2]; v1.w = X1[4*i+3];
            vmax = fmaxf(vmax, fmaxf(fmaxf(v0.x, v0.y), fmaxf(v0.z, v0.w)));
            vmax = fmaxf(vmax, fmaxf(fmaxf(v1.x, v1.y), fmaxf(v1.z, v1.w)));
            o0[i] = v0;
            o1[i] = v1;
        }
    }

    #pragma unroll
    for (int off = 32; off > 0; off >>= 1)
        vmax = fmaxf(vmax, __shfl_xor(vmax, off, 64));
    if ((t & 63) == 0) wmax[t >> 6] = vmax;
    __syncthreads();
    if (t == 0)
        bmax_out[blockIdx.x] = fmaxf(fmaxf(wmax[0], wmax[1]), fmaxf(wmax[2], wmax[3]));
}

// Normalize; each block re-reduces the 512 per-block maxes itself.
__global__ __launch_bounds__(256) void cassi_norm(float* __restrict__ out,
                                                  const float* __restrict__ bmax)
{
    __shared__ float wm[4];
    const int t = threadIdx.x;
    float v = fmaxf(bmax[t], bmax[t + 256]);
    #pragma unroll
    for (int off = 32; off > 0; off >>= 1)
        v = fmaxf(v, __shfl_xor(v, off, 64));
    if ((t & 63) == 0) wm[t >> 6] = v;
    __syncthreads();
    const float inv = 1.f / fmaxf(fmaxf(wm[0], wm[1]), fmaxf(wm[2], wm[3]));
    const int i = (blockIdx.x * 256 + t) * 4;
    float4 q = *reinterpret_cast<float4*>(out + i);
    q.x *= inv; q.y *= inv; q.z *= inv; q.w *= inv;
    *reinterpret_cast<float4*>(out + i) = q;
}

extern "C" void kernel_launch(void* const* d_in, const int* in_sizes, int n_in,
                              void* d_out, int out_size, void* d_ws, size_t ws_size,
                              hipStream_t stream) {
    const float* x  = (const float*)d_in[0];
    const float* wr = (const float*)d_in[1];
    const float* wg = (const float*)d_in[2];
    const float* wb = (const float*)d_in[3];
    const float* wc = (const float*)d_in[4];
    float* out  = (float*)d_out;
    float* bmax = (float*)d_ws;          // 512 per-block maxes (2KB)

    cassi_fused<<<2 * M_, 256, 0, stream>>>(x, wr, wg, wb, wc, out, bmax);
    const int n4blocks = (B_ * M_ * N_ * L_) / 4 / 256;     // 6144, exact
    cassi_norm<<<n4blocks, 256, 0, stream>>>(out, bmax);
}